// Round 16
// baseline (131.021 us; speedup 1.0000x reference)
//
#include <hip/hip_runtime.h>
#include <hip/hip_bf16.h>
#include <stdint.h>

#define NTOK 4096
#define DIM  1024

typedef unsigned short u16;
typedef __bf16 bf16x8 __attribute__((ext_vector_type(8)));
typedef float f32x4 __attribute__((ext_vector_type(4)));
typedef u16 u16x8 __attribute__((ext_vector_type(8)));

// ---------- helpers ----------
__device__ __forceinline__ u16 f2bf(float f) {
  union { float f; uint32_t u; } c; c.f = f;
  return (u16)((c.u + 0x7fffu + ((c.u >> 16) & 1u)) >> 16);  // RNE
}
__device__ __forceinline__ float bf2f(u16 b) {
  union { uint32_t u; float f; } c; c.u = (uint32_t)b << 16;
  return c.f;
}

__device__ __forceinline__ float wave_max(float v) {
#pragma unroll
  for (int o = 32; o; o >>= 1) v = fmaxf(v, __shfl_xor(v, o, 64));
  return v;
}
__device__ __forceinline__ float wave_sum(float v) {
#pragma unroll
  for (int o = 32; o; o >>= 1) v += __shfl_xor(v, o, 64);
  return v;
}

// bijective XCD swizzle (m204)
__device__ __forceinline__ int xcd_swz(int orig, int nwg) {
  const int q = nwg >> 3, r = nwg & 7;
  const int x = orig & 7, i = orig >> 3;
  return (x < r ? x * (q + 1) : r * (q + 1) + (x - r) * q) + i;
}

// async global->LDS, 16B/lane; LDS dest wave-uniform base (HW adds lane*16).
__device__ __forceinline__ void gld16(const u16* g, u16* l) {
  __builtin_amdgcn_global_load_lds((const __attribute__((address_space(1))) void*)g,
                                   (__attribute__((address_space(3))) void*)l, 16, 0, 0);
}

template<int N> __device__ __forceinline__ void wait_vmcnt() {
  if constexpr (N == 0) asm volatile("s_waitcnt vmcnt(0)" ::: "memory");
  else if constexpr (N == 6) asm volatile("s_waitcnt vmcnt(6)" ::: "memory");
  else if constexpr (N == 8) asm volatile("s_waitcnt vmcnt(8)" ::: "memory");
}

#define SFENCE() __builtin_amdgcn_sched_barrier(0)
#define BAR()    __builtin_amdgcn_s_barrier()
// load-bearing fences only (m141: over-pinning regresses):
//  - LGKM0F: trailing SFENCE pins MFMA below the wait (rule 18)
//  - VMC6F/VMC0F: leading SFENCE pins stage-issues above the counted vmcnt
//    (ledger integrity); trailing SFENCE pins subsequent reads below.
#define LGKM0F() do { asm volatile("s_waitcnt lgkmcnt(0)" ::: "memory"); SFENCE(); } while (0)
#define VMC6F()  do { SFENCE(); asm volatile("s_waitcnt vmcnt(6)" ::: "memory"); SFENCE(); } while (0)
#define VMC0F()  do { SFENCE(); asm volatile("s_waitcnt vmcnt(0)" ::: "memory"); SFENCE(); } while (0)

// ============================================================================
// fp32 -> bf16 conversion, 8 elems/thread. z<6 selects tensor; z==6 zeroes
// out rows >= 2048 (split-K atomicAdd targets) at full-grid BW.
// ============================================================================
__global__ __launch_bounds__(256) void cvt6(
    const float* __restrict__ qx, const float* __restrict__ kx, const float* __restrict__ vx,
    const float* __restrict__ Wq, const float* __restrict__ Wk, const float* __restrict__ Wv,
    u16* __restrict__ qxb, u16* __restrict__ kxb, u16* __restrict__ vxb,
    u16* __restrict__ Wqb, u16* __restrict__ Wkb, u16* __restrict__ Wvb,
    float* __restrict__ outZero)
{
  const int z = blockIdx.z;
  const int i = (blockIdx.x * 256 + threadIdx.x) * 8;
  if (z == 6) {  // zero out[2048:4096][*]
    if (i >= 2048 * DIM) return;
    const float4 zz = {0.f, 0.f, 0.f, 0.f};
    *reinterpret_cast<float4*>(outZero + i) = zz;
    *reinterpret_cast<float4*>(outZero + i + 4) = zz;
    return;
  }
  const int nelem = (z < 3) ? NTOK * DIM : DIM * DIM;
  if (i >= nelem) return;
  const float* in = (z == 0) ? qx : (z == 1) ? kx : (z == 2) ? vx
                  : (z == 3) ? Wq : (z == 4) ? Wk : Wv;
  u16* out = (z == 0) ? qxb : (z == 1) ? kxb : (z == 2) ? vxb
           : (z == 3) ? Wqb : (z == 4) ? Wkb : Wvb;
  float4 a = *reinterpret_cast<const float4*>(in + i);
  float4 b = *reinterpret_cast<const float4*>(in + i + 4);
  u16x8 o;
  o[0] = f2bf(a.x); o[1] = f2bf(a.y); o[2] = f2bf(a.z); o[3] = f2bf(a.w);
  o[4] = f2bf(b.x); o[5] = f2bf(b.y); o[6] = f2bf(b.z); o[7] = f2bf(b.w);
  *reinterpret_cast<u16x8*>(out + i) = o;
}

// ============================================================================
// 8-PHASE 256x256 CORE — strip-region layout (R14-proven correct), fences
// relaxed to the load-bearing set (see macros). Region(mh) == read footprint:
//   A region(mh) = strips {j*128+mh*64+[0,64) : j=0,1}
//   B region(nh) = strips {s*64 +nh*32+[0,32) : s=0..3}
// LDS: parity p at p*32768 u16; A regions at mh*8192 (strip j at j*4096,
// row-in-strip rr at rr*64); B at 16384+nh*8192 (strip s at s*2048).
// Swizzle: physical chunk c holds global chunk c^(rr&7) (0 conflicts).
// Stage lag: A-h1(t+1)@ph1; A-h0,B-h0,B-h1(t+2)@ph2-4. vmcnt(6) only @ph4.
// Safety argument for relaxed fences: all reads of tile t occur after the
// SFENCE'd VMC6F of iter t-1 (stage-landed guarantee); all region overwrites
// are >= 1 barrier after that region's reads; the vmcnt ledger only needs
// stages pinned above VMC6F (its leading SFENCE). Barrier-adjacent motion
// cannot cross any waitcnt fence.
// ============================================================================
__device__ __forceinline__ void mm256(
    const u16* __restrict__ A, const u16* __restrict__ B,
    int lda, int ldb, int row0, int col0, int nt,
    u16* lds, f32x4 (&acc)[8][4])
{
  const int tid = threadIdx.x;
  const int wv = tid >> 6, lane = tid & 63;
  const int wm = wv >> 2, wn = wv & 3;
  const int l15 = lane & 15, l4 = lane >> 4;
  const int r8 = lane >> 3;
  const int gch = ((lane & 7) ^ r8) << 3;  // pre-swizzled global elem offset

  const int aStrip = wv >> 2;
  const int aSub   = (wv & 3) * 16;
  const int bStrip = wv >> 1;
  const int bSub   = (wv & 1) * 16;

  auto stageA = [&](int parity, int mh, int kt) {
    const int kofs = kt << 6;
#pragma unroll
    for (int jj = 0; jj < 2; ++jj) {
      const int rr = aSub + jj * 8;
      const int grow = row0 + aStrip * 128 + mh * 64 + rr + r8;
      u16* d = lds + parity * 32768 + mh * 8192 + aStrip * 4096 + rr * 64;
      gld16(A + (size_t)grow * lda + gch + kofs, d);
    }
  };
  auto stageB = [&](int parity, int nh, int kt) {
    const int kofs = kt << 6;
#pragma unroll
    for (int jj = 0; jj < 2; ++jj) {
      const int rr = bSub + jj * 8;
      const int grow = col0 + bStrip * 64 + nh * 32 + rr + r8;
      u16* d = lds + parity * 32768 + 16384 + nh * 8192 + bStrip * 2048 + rr * 64;
      gld16(B + (size_t)grow * ldb + gch + kofs, d);
    }
  };

  bf16x8 af[4][2];
  bf16x8 bfr[2][2][2];

  auto read_af = [&](int parity, int mh) {
#pragma unroll
    for (int mf = 0; mf < 4; ++mf)
#pragma unroll
      for (int ks = 0; ks < 2; ++ks) {
        const int rr = mf * 16 + l15;
        af[mf][ks] = *reinterpret_cast<const bf16x8*>(
            lds + parity * 32768 + mh * 8192 + wm * 4096 + rr * 64 +
            ((((ks << 2) + l4) ^ (rr & 7)) << 3));
      }
  };
  auto read_bf = [&](int parity, int nh) {
#pragma unroll
    for (int nf = 0; nf < 2; ++nf)
#pragma unroll
      for (int ks = 0; ks < 2; ++ks) {
        const int rr = nf * 16 + l15;
        bfr[nh][nf][ks] = *reinterpret_cast<const bf16x8*>(
            lds + parity * 32768 + 16384 + nh * 8192 + wn * 2048 + rr * 64 +
            ((((ks << 2) + l4) ^ (rr & 7)) << 3));
      }
  };
  auto quad = [&](int mh, int nh) {
    __builtin_amdgcn_s_setprio(1);
#pragma unroll
    for (int mf = 0; mf < 4; ++mf)
#pragma unroll
      for (int nf = 0; nf < 2; ++nf)
#pragma unroll
        for (int ks = 0; ks < 2; ++ks)
          acc[mh * 4 + mf][nh * 2 + nf] = __builtin_amdgcn_mfma_f32_16x16x32_bf16(
              af[mf][ks], bfr[nh][nf][ks], acc[mh * 4 + mf][nh * 2 + nf], 0, 0, 0);
    __builtin_amdgcn_s_setprio(0);
  };

  // prologue: t0 all 4 regions + t1 {A-h0, B-h0, B-h1}; full drain so the
  // counted-vmcnt ledger is independent of prologue issue order.
  stageA(0, 0, 0); stageA(0, 1, 0); stageB(0, 0, 0); stageB(0, 1, 0);
  const int t1 = (nt > 1) ? 1 : 0;
  stageA(1, 0, t1); stageB(1, 0, t1); stageB(1, 1, t1);
  VMC0F();
  BAR();

  for (int t = 0; t < nt; ++t) {
    const int par = t & 1, nxt = par ^ 1;
    const int tp1 = (t + 1 < nt) ? t + 1 : nt - 1;
    const int tp2 = (t + 2 < nt) ? t + 2 : nt - 1;
    // ph1: ds-read A-h0 + B-h0 (12 reads); stage A-h1(t+1)
    read_af(par, 0); read_bf(par, 0);
    stageA(nxt, 1, tp1);
    BAR(); LGKM0F();
    quad(0, 0);
    BAR();
    // ph2: ds-read B-h1; stage A-h0(t+2) [A-h0(par) fully read at ph1]
    read_bf(par, 1);
    stageA(par, 0, tp2);
    BAR(); LGKM0F();
    quad(0, 1);
    BAR();
    // ph3: ds-read A-h1; stage B-h0(t+2) [B-h0(par) fully read at ph1]
    read_af(par, 1);
    stageB(par, 0, tp2);
    BAR(); LGKM0F();
    quad(1, 0);
    BAR();
    // ph4: stage B-h1(t+2); counted vmcnt -> tile t+1 fully landed
    stageB(par, 1, tp2);
    VMC6F();
    BAR();
    quad(1, 1);
    BAR();
  }

  VMC0F();  // drain: stray loads write LDS, must not outlive the block
}

// ============================================================================
// Projections on the 8-phase core: y = x @ W^T. grid 192 = 3 x (16by x 4bx),
// XCD-swizzled. z=2 stores v transposed [DIM,NTOK].
// ============================================================================
__global__ __launch_bounds__(512, 2) void proj256(
    const u16* __restrict__ qxb, const u16* __restrict__ kxb, const u16* __restrict__ vxb,
    const u16* __restrict__ Wqb, const u16* __restrict__ Wkb, const u16* __restrict__ Wvb,
    u16* __restrict__ qb, u16* __restrict__ kb, u16* __restrict__ vT)
{
  __shared__ alignas(16) u16 lds[65536];  // 128 KB
  const int w = xcd_swz(blockIdx.x, 192);
  const int z = w >> 6, rem = w & 63;
  const int by = rem >> 2, bx = rem & 3;
  const u16* A = (z == 0) ? qxb : (z == 1) ? kxb : vxb;
  const u16* B = (z == 0) ? Wqb : (z == 1) ? Wkb : Wvb;
  const int row0 = by * 256, col0 = bx * 256;

  f32x4 acc[8][4] = {};
  mm256(A, B, DIM, DIM, row0, col0, DIM / 64, lds, acc);

  const int wv = threadIdx.x >> 6, lane = threadIdx.x & 63;
  const int wm = wv >> 2, wn = wv & 3;
  const int l15 = lane & 15, l4 = lane >> 4;
  const int om = row0 + wm * 128;
  const int on = col0 + wn * 64;
  if (z < 2) {
    u16* C = (z == 0) ? qb : kb;
#pragma unroll
    for (int m = 0; m < 8; ++m)
#pragma unroll
      for (int n = 0; n < 4; ++n)
#pragma unroll
        for (int r = 0; r < 4; ++r)
          C[(size_t)(om + m * 16 + l4 * 4 + r) * DIM + (on + n * 16 + l15)] = f2bf(acc[m][n][r]);
  } else {
#pragma unroll
    for (int m = 0; m < 8; ++m)
#pragma unroll
      for (int n = 0; n < 4; ++n) {
        ushort4 o;
        o.x = f2bf(acc[m][n][0]); o.y = f2bf(acc[m][n][1]);
        o.z = f2bf(acc[m][n][2]); o.w = f2bf(acc[m][n][3]);
        *reinterpret_cast<ushort4*>(&vT[(size_t)(on + n * 16 + l15) * NTOK + (om + m * 16 + l4 * 4)]) = o;
      }
  }
}

// ============================================================================
// Scores on the 8-phase core: S = (q @ k^T)*scale, bf16 out. 136 triangle
// tiles of 256x256 (bx <= by), XCD-swizzled.
// ============================================================================
__global__ __launch_bounds__(512, 2) void scores256(
    const u16* __restrict__ A, const u16* __restrict__ B, u16* __restrict__ C, float scale)
{
  __shared__ alignas(16) u16 lds[65536];  // 128 KB
  const int t = xcd_swz(blockIdx.x, 136);
  int by = (int)((sqrtf(8.0f * t + 1.0f) - 1.0f) * 0.5f);
  while ((by + 1) * (by + 2) / 2 <= t) ++by;
  while (by * (by + 1) / 2 > t) --by;
  const int bx = t - by * (by + 1) / 2;
  const int row0 = by * 256, col0 = bx * 256;

  f32x4 acc[8][4] = {};
  mm256(A, B, DIM, DIM, row0, col0, DIM / 64, lds, acc);

  const int wv = threadIdx.x >> 6, lane = threadIdx.x & 63;
  const int wm = wv >> 2, wn = wv & 3;
  const int l15 = lane & 15, l4 = lane >> 4;
  const int om = row0 + wm * 128;
  const int on = col0 + wn * 64;
#pragma unroll
  for (int m = 0; m < 8; ++m)
#pragma unroll
    for (int n = 0; n < 4; ++n)
#pragma unroll
      for (int r = 0; r < 4; ++r)
        C[(size_t)(om + m * 16 + l4 * 4 + r) * NTOK + (on + n * 16 + l15)] = f2bf(acc[m][n][r] * scale);
}

// ============================================================================
// PV core (R8-proven, untouched): BK=64, 1-deep counted-vmcnt dbuf, 4 waves.
// ============================================================================
__device__ __forceinline__ void mm64(
    const u16* __restrict__ A, const u16* __restrict__ B,
    int lda, int ldb, int klo, int khi, int row0, int col0,
    u16* sA, u16* sB, f32x4 (&acc)[2][4])
{
  constexpr int ASZ = 64 * 64, BSZ = 128 * 64;
  const int tid = threadIdx.x;
  const int wave = tid >> 6, lane = tid & 63;
  const int wr = wave >> 1, wc = wave & 1;
  const int l15 = lane & 15, l4 = lane >> 4;
  const int h = l15 & 7;

  const int srow = lane >> 3;
  const int scol = ((lane & 7) ^ (lane >> 3)) << 3;
  const u16* gA = A + (size_t)(row0 + wave * 16 + srow) * lda + scol;
  const u16* gB = B + (size_t)(col0 + wave * 32 + srow) * ldb + scol;
  const int lbA = wave * 16 * 64;
  const int lbB = wave * 32 * 64;

  auto stage = [&](int k0, u16* bA, u16* bB) {
#pragma unroll
    for (int i = 0; i < 2; ++i)
      gld16(gA + (size_t)(i * 8) * lda + k0, bA + lbA + i * 512);
#pragma unroll
    for (int i = 0; i < 4; ++i)
      gld16(gB + (size_t)(i * 8) * ldb + k0, bB + lbB + i * 512);
  };

  stage(klo, sA, sB);
  int cur = 0;
  for (int k0 = klo; k0 < khi; k0 += 64) {
    const bool more = (k0 + 64 < khi);
    if (more) {
      stage(k0 + 64, sA + (cur ^ 1) * ASZ, sB + (cur ^ 1) * BSZ);
      SFENCE(); wait_vmcnt<6>(); SFENCE();
    } else {
      SFENCE(); wait_vmcnt<0>(); SFENCE();
    }
    __builtin_amdgcn_s_barrier();
    SFENCE();

    const char* bA = (const char*)(sA + cur * ASZ);
    const char* bB = (const char*)(sB + cur * BSZ);
#pragma unroll
    for (int ks = 0; ks < 2; ++ks) {
      bf16x8 af[2], bfv[4];
#pragma unroll
      for (int mf = 0; mf < 2; ++mf)
        af[mf] = *reinterpret_cast<const bf16x8*>(
            bA + ((wr * 32 + mf * 16 + l15) << 7) + ((((ks << 2) + l4) ^ h) << 4));
#pragma unroll
      for (int nf = 0; nf < 4; ++nf)
        bfv[nf] = *reinterpret_cast<const bf16x8*>(
            bB + ((wc * 64 + nf * 16 + l15) << 7) + ((((ks << 2) + l4) ^ h) << 4));
#pragma unroll
      for (int mf = 0; mf < 2; ++mf)
#pragma unroll
        for (int nf = 0; nf < 4; ++nf)
          acc[mf][nf] = __builtin_amdgcn_mfma_f32_16x16x32_bf16(af[mf], bfv[nf], acc[mf][nf], 0, 0, 0);
    }

    SFENCE();
    __builtin_amdgcn_s_barrier();
    SFENCE();
    cur ^= 1;
  }
}

// ============================================================================
// PV: out = P @ vT^T. 64x128 tiles, 1-D grid 768 = 96 chunks x 8 bx.
// by<32: single chunk. by>=32: 2-way split-K, both halves atomicAdd into
// pre-zeroed out (zeroed by cvt6 z=6; 2 addends -> deterministic).
// ============================================================================
__global__ __launch_bounds__(256) void gemm_pv(
    const u16* __restrict__ P, const u16* __restrict__ vT, float* __restrict__ C)
{
  __shared__ alignas(16) u16 sA[2 * 64 * 64];
  __shared__ alignas(16) u16 sB[2 * 128 * 64];
  const int w = xcd_swz(blockIdx.x, 768);
  const int bx = w & 7;
  const int cid = w >> 3;  // 0..95
  int by, half;
  if (cid < 32) { by = cid; half = -1; }
  else { const int j = cid - 32; by = 32 + (j >> 1); half = j & 1; }
  const int row0 = by * 64, col0 = bx * 128;
  const int Klim = row0 + 64;
  int klo = 0, khi = Klim;
  if (half >= 0) {
    const int h1 = (((Klim >> 6) + 1) >> 1) << 6;
    if (half == 0) khi = h1; else klo = h1;
  }

  f32x4 acc[2][4] = {};
  mm64(P, vT, NTOK, NTOK, klo, khi, row0, col0, sA, sB, acc);

  const int lane = threadIdx.x & 63;
  const int wave = threadIdx.x >> 6;
  const int l15 = lane & 15, l4 = lane >> 4;
  const int om = row0 + (wave >> 1) * 32;
  const int on = col0 + (wave & 1) * 64;
#pragma unroll
  for (int mf = 0; mf < 2; ++mf)
#pragma unroll
    for (int nf = 0; nf < 4; ++nf)
#pragma unroll
      for (int r = 0; r < 4; ++r) {
        const size_t idx = (size_t)(om + mf * 16 + l4 * 4 + r) * DIM + (on + nf * 16 + l15);
        if (half >= 0) atomicAdd(&C[idx], acc[mf][nf][r]);
        else C[idx] = acc[mf][nf][r];
      }
}

// ---------- causal row softmax: S bf16 -> P bf16, cols < (row&~127)+128 ----------
// 512 threads/block: one 4096-elem pass covers the longest row.
__global__ __launch_bounds__(512) void softmax_causal(const u16* __restrict__ S,
                                                      u16* __restrict__ P) {
  __shared__ float buf[NTOK];
  __shared__ float red[16];
  const int row = blockIdx.x;
  const int tid = threadIdx.x;
  const int wid = tid >> 6;
  const int limit = row + 1;
  const int limit128 = (row & ~127) + 128;
  const u16* srow = S + (size_t)row * NTOK;

  float lmax = -1e30f;
  for (int j = tid * 8; j < limit128; j += 4096) {
    float v[8];
    if (j + 8 <= limit) {
      u16x8 sv = *reinterpret_cast<const u16x8*>(srow + j);
#pragma unroll
      for (int e = 0; e < 8; ++e) v[e] = bf2f(sv[e]);
    } else {
#pragma unroll
      for (int e = 0; e < 8; ++e) v[e] = (j + e < limit) ? bf2f(srow[j + e]) : -1e30f;
    }
    float4 lo = {v[0], v[1], v[2], v[3]}, hi = {v[4], v[5], v[6], v[7]};
    *reinterpret_cast<float4*>(buf + j) = lo;
    *reinterpret_cast<float4*>(buf + j + 4) = hi;
#pragma unroll
    for (int e = 0; e < 8; ++e) lmax = fmaxf(lmax, v[e]);
  }
  lmax = wave_max(lmax);
  if ((tid & 63) == 0) red[wid] = lmax;
  __syncthreads();
  float m = red[0];
#pragma unroll
  for (int i = 1; i < 8; ++i) m = fmaxf(m, red[i]);

  float lsum = 0.f;
  for (int j = tid * 8; j < limit128; j += 4096) {
    float4 lo = *reinterpret_cast<float4*>(buf + j);
    float4 hi = *reinterpret_cast<float4*>(buf + j + 4);
    float e0 = __expf(lo.x - m), e1 = __expf(lo.y - m), e2 = __expf(lo.z - m), e3 = __expf(lo.w - m);
    float e4 = __expf(hi.x - m), e5 = __expf(hi.y - m), e6 = __expf(hi.z - m), e7 = __expf(hi.w - m);
    float4 eo = {e0, e1, e2, e3}, eh = {e4, e5, e6, e7};
    *reinterpret_cast<float4*>(buf + j) = eo;
    *reinterpret_cast<float4*>(buf + j + 4) = eh;
    lsum += ((e0 + e1) + (e2 + e3)) + ((e4 + e5) + (e6 + e7));
  }
  lsum = wave_sum(lsum);
  if ((tid & 63) == 0) red[8 + wid] = lsum;
  __syncthreads();
  float s = red[8];
#pragma unroll
  for (int i = 1; i < 8; ++i) s += red[8 + i];
  const float inv = 1.0f / s;

  u16* prow = P + (size_t)row * NTOK;
  for (int j = tid * 8; j < limit128; j += 4096) {
    float4 lo = *reinterpret_cast<float4*>(buf + j);
    float4 hi = *reinterpret_cast<float4*>(buf + j + 4);
    u16x8 o;
    o[0] = f2bf(lo.x * inv); o[1] = f2bf(lo.y * inv);
    o[2] = f2bf(lo.z * inv); o[3] = f2bf(lo.w * inv);
    o[4] = f2bf(hi.x * inv); o[5] = f2bf(hi.y * inv);
    o[6] = f2bf(hi.z * inv); o[7] = f2bf(hi.w * inv);
    *reinterpret_cast<u16x8*>(prow + j) = o;
  }
}

// ---------- launcher ----------
extern "C" void kernel_launch(void* const* d_in, const int* in_sizes, int n_in,
                              void* d_out, int out_size, void* d_ws, size_t ws_size,
                              hipStream_t stream) {
  const float* qx = (const float*)d_in[0];
  const float* kx = (const float*)d_in[1];
  const float* vx = (const float*)d_in[2];
  const float* Wq = (const float*)d_in[3];
  const float* Wk = (const float*)d_in[4];
  const float* Wv = (const float*)d_in[5];
  float* out = (float*)d_out;
  char* ws = (char*)d_ws;
  const size_t MB = 1024ull * 1024ull;

  if (ws_size < 120 * MB) {
    hipMemsetAsync(d_out, 0xFF, (size_t)out_size * sizeof(float), stream);
    return;
  }

  // ws layout: [0,30) cvt bf16 (dead after proj) | [0,32) S bf16 (after proj)
  //            [64,72) qb | [72,80) kb | [80,88) vT | [88,120) P
  u16* qxb = (u16*)(ws);
  u16* kxb = (u16*)(ws + 8 * MB);
  u16* vxb = (u16*)(ws + 16 * MB);
  u16* Wqb = (u16*)(ws + 24 * MB);
  u16* Wkb = (u16*)(ws + 26 * MB);
  u16* Wvb = (u16*)(ws + 28 * MB);
  u16* S   = (u16*)(ws);
  u16* qb  = (u16*)(ws + 64 * MB);
  u16* kb  = (u16*)(ws + 72 * MB);
  u16* vT  = (u16*)(ws + 80 * MB);
  u16* P   = (u16*)(ws + 88 * MB);

  cvt6<<<dim3(NTOK * DIM / (256 * 8), 1, 7), 256, 0, stream>>>(
      qx, kx, vx, Wq, Wk, Wv, qxb, kxb, vxb, Wqb, Wkb, Wvb,
      out + (size_t)2048 * DIM);

  proj256<<<192, 512, 0, stream>>>(qxb, kxb, vxb, Wqb, Wkb, Wvb, qb, kb, vT);

  scores256<<<136, 512, 0, stream>>>(qb, kb, S, 0.03125f);

  softmax_causal<<<NTOK, 512, 0, stream>>>(S, P);

  gemm_pv<<<768, 256, 0, stream>>>(P, vT, out);
}

// Round 17
// 127.451 us; speedup vs baseline: 1.0280x; 1.0280x over previous
//
#include <hip/hip_runtime.h>
#include <hip/hip_bf16.h>
#include <stdint.h>

#define NTOK 4096
#define DIM  1024

typedef unsigned short u16;
typedef __bf16 bf16x8 __attribute__((ext_vector_type(8)));
typedef float f32x4 __attribute__((ext_vector_type(4)));
typedef u16 u16x8 __attribute__((ext_vector_type(8)));

// ---------- helpers ----------
__device__ __forceinline__ u16 f2bf(float f) {
  union { float f; uint32_t u; } c; c.f = f;
  return (u16)((c.u + 0x7fffu + ((c.u >> 16) & 1u)) >> 16);  // RNE
}
__device__ __forceinline__ float bf2f(u16 b) {
  union { uint32_t u; float f; } c; c.u = (uint32_t)b << 16;
  return c.f;
}

__device__ __forceinline__ float wave_max(float v) {
#pragma unroll
  for (int o = 32; o; o >>= 1) v = fmaxf(v, __shfl_xor(v, o, 64));
  return v;
}
__device__ __forceinline__ float wave_sum(float v) {
#pragma unroll
  for (int o = 32; o; o >>= 1) v += __shfl_xor(v, o, 64);
  return v;
}

// bijective XCD swizzle (m204)
__device__ __forceinline__ int xcd_swz(int orig, int nwg) {
  const int q = nwg >> 3, r = nwg & 7;
  const int x = orig & 7, i = orig >> 3;
  return (x < r ? x * (q + 1) : r * (q + 1) + (x - r) * q) + i;
}

// async global->LDS, 16B/lane; LDS dest wave-uniform base (HW adds lane*16).
__device__ __forceinline__ void gld16(const u16* g, u16* l) {
  __builtin_amdgcn_global_load_lds((const __attribute__((address_space(1))) void*)g,
                                   (__attribute__((address_space(3))) void*)l, 16, 0, 0);
}

template<int N> __device__ __forceinline__ void wait_vmcnt() {
  if constexpr (N == 0) asm volatile("s_waitcnt vmcnt(0)" ::: "memory");
  else if constexpr (N == 6) asm volatile("s_waitcnt vmcnt(6)" ::: "memory");
  else if constexpr (N == 8) asm volatile("s_waitcnt vmcnt(8)" ::: "memory");
}

#define SFENCE() __builtin_amdgcn_sched_barrier(0)
#define BARF()   do { SFENCE(); __builtin_amdgcn_s_barrier(); SFENCE(); } while (0)
#define LGKM0F() do { SFENCE(); asm volatile("s_waitcnt lgkmcnt(0)" ::: "memory"); SFENCE(); } while (0)
#define VMC6F()  do { SFENCE(); asm volatile("s_waitcnt vmcnt(6)" ::: "memory"); SFENCE(); } while (0)
#define VMC0F()  do { SFENCE(); asm volatile("s_waitcnt vmcnt(0)" ::: "memory"); SFENCE(); } while (0)

// ============================================================================
// fp32 -> bf16 conversion, 8 elems/thread. z<6 selects tensor; z==6 zeroes
// out rows >= 2048 (split-K atomicAdd targets) at full-grid BW.
// ============================================================================
__global__ __launch_bounds__(256) void cvt6(
    const float* __restrict__ qx, const float* __restrict__ kx, const float* __restrict__ vx,
    const float* __restrict__ Wq, const float* __restrict__ Wk, const float* __restrict__ Wv,
    u16* __restrict__ qxb, u16* __restrict__ kxb, u16* __restrict__ vxb,
    u16* __restrict__ Wqb, u16* __restrict__ Wkb, u16* __restrict__ Wvb,
    float* __restrict__ outZero)
{
  const int z = blockIdx.z;
  const int i = (blockIdx.x * 256 + threadIdx.x) * 8;
  if (z == 6) {  // zero out[2048:4096][*]
    if (i >= 2048 * DIM) return;
    const float4 zz = {0.f, 0.f, 0.f, 0.f};
    *reinterpret_cast<float4*>(outZero + i) = zz;
    *reinterpret_cast<float4*>(outZero + i + 4) = zz;
    return;
  }
  const int nelem = (z < 3) ? NTOK * DIM : DIM * DIM;
  if (i >= nelem) return;
  const float* in = (z == 0) ? qx : (z == 1) ? kx : (z == 2) ? vx
                  : (z == 3) ? Wq : (z == 4) ? Wk : Wv;
  u16* out = (z == 0) ? qxb : (z == 1) ? kxb : (z == 2) ? vxb
           : (z == 3) ? Wqb : (z == 4) ? Wkb : Wvb;
  float4 a = *reinterpret_cast<const float4*>(in + i);
  float4 b = *reinterpret_cast<const float4*>(in + i + 4);
  u16x8 o;
  o[0] = f2bf(a.x); o[1] = f2bf(a.y); o[2] = f2bf(a.z); o[3] = f2bf(a.w);
  o[4] = f2bf(b.x); o[5] = f2bf(b.y); o[6] = f2bf(b.z); o[7] = f2bf(b.w);
  *reinterpret_cast<u16x8*>(out + i) = o;
}

// ============================================================================
// 8-PHASE 256x256 CORE — strip-region layout (R14-proven correct).
// Region(mh) == exact read footprint:
//   A region(mh) = strips {j*128+mh*64+[0,64) : j=0,1}
//   B region(nh) = strips {s*64 +nh*32+[0,32) : s=0..3}
// LDS: parity p at p*32768 u16; A regions at mh*8192 (strip j at j*4096,
// row-in-strip rr at rr*64); B at 16384+nh*8192 (strip s at s*2048).
// Swizzle: physical chunk c holds global chunk c^(rr&7) (0 conflicts).
// Stage lag: A-h1(t+1)@ph1; A-h0,B-h0,B-h1(t+2)@ph2-4. vmcnt(6) only @ph4.
// Prologue + exit drain vmcnt(0).
// ============================================================================
__device__ __forceinline__ void mm256(
    const u16* __restrict__ A, const u16* __restrict__ B,
    int lda, int ldb, int row0, int col0, int nt,
    u16* lds, f32x4 (&acc)[8][4])
{
  const int tid = threadIdx.x;
  const int wv = tid >> 6, lane = tid & 63;
  const int wm = wv >> 2, wn = wv & 3;
  const int l15 = lane & 15, l4 = lane >> 4;
  const int r8 = lane >> 3;
  const int gch = ((lane & 7) ^ r8) << 3;  // pre-swizzled global elem offset

  const int aStrip = wv >> 2;
  const int aSub   = (wv & 3) * 16;
  const int bStrip = wv >> 1;
  const int bSub   = (wv & 1) * 16;

  auto stageA = [&](int parity, int mh, int kt) {
    const int kofs = kt << 6;
#pragma unroll
    for (int jj = 0; jj < 2; ++jj) {
      const int rr = aSub + jj * 8;
      const int grow = row0 + aStrip * 128 + mh * 64 + rr + r8;
      u16* d = lds + parity * 32768 + mh * 8192 + aStrip * 4096 + rr * 64;
      gld16(A + (size_t)grow * lda + gch + kofs, d);
    }
  };
  auto stageB = [&](int parity, int nh, int kt) {
    const int kofs = kt << 6;
#pragma unroll
    for (int jj = 0; jj < 2; ++jj) {
      const int rr = bSub + jj * 8;
      const int grow = col0 + bStrip * 64 + nh * 32 + rr + r8;
      u16* d = lds + parity * 32768 + 16384 + nh * 8192 + bStrip * 2048 + rr * 64;
      gld16(B + (size_t)grow * ldb + gch + kofs, d);
    }
  };

  bf16x8 af[4][2];
  bf16x8 bfr[2][2][2];

  auto read_af = [&](int parity, int mh) {
#pragma unroll
    for (int mf = 0; mf < 4; ++mf)
#pragma unroll
      for (int ks = 0; ks < 2; ++ks) {
        const int rr = mf * 16 + l15;
        af[mf][ks] = *reinterpret_cast<const bf16x8*>(
            lds + parity * 32768 + mh * 8192 + wm * 4096 + rr * 64 +
            ((((ks << 2) + l4) ^ (rr & 7)) << 3));
      }
  };
  auto read_bf = [&](int parity, int nh) {
#pragma unroll
    for (int nf = 0; nf < 2; ++nf)
#pragma unroll
      for (int ks = 0; ks < 2; ++ks) {
        const int rr = nf * 16 + l15;
        bfr[nh][nf][ks] = *reinterpret_cast<const bf16x8*>(
            lds + parity * 32768 + 16384 + nh * 8192 + wn * 2048 + rr * 64 +
            ((((ks << 2) + l4) ^ (rr & 7)) << 3));
      }
  };
  auto quad = [&](int mh, int nh) {
    __builtin_amdgcn_s_setprio(1);
#pragma unroll
    for (int mf = 0; mf < 4; ++mf)
#pragma unroll
      for (int nf = 0; nf < 2; ++nf)
#pragma unroll
        for (int ks = 0; ks < 2; ++ks)
          acc[mh * 4 + mf][nh * 2 + nf] = __builtin_amdgcn_mfma_f32_16x16x32_bf16(
              af[mf][ks], bfr[nh][nf][ks], acc[mh * 4 + mf][nh * 2 + nf], 0, 0, 0);
    __builtin_amdgcn_s_setprio(0);
  };

  // prologue: t0 all 4 regions + t1 {A-h0, B-h0, B-h1}; full drain.
  stageA(0, 0, 0); SFENCE();
  stageA(0, 1, 0); SFENCE();
  stageB(0, 0, 0); SFENCE();
  stageB(0, 1, 0); SFENCE();
  const int t1 = (nt > 1) ? 1 : 0;
  stageA(1, 0, t1); SFENCE();
  stageB(1, 0, t1); SFENCE();
  stageB(1, 1, t1); SFENCE();
  VMC0F();
  BARF();

  for (int t = 0; t < nt; ++t) {
    const int par = t & 1, nxt = par ^ 1;
    const int tp1 = (t + 1 < nt) ? t + 1 : nt - 1;
    const int tp2 = (t + 2 < nt) ? t + 2 : nt - 1;
    // ph1
    read_af(par, 0); read_bf(par, 0);
    stageA(nxt, 1, tp1);
    BARF(); LGKM0F();
    quad(0, 0);
    BARF();
    // ph2
    read_bf(par, 1);
    stageA(par, 0, tp2);
    BARF(); LGKM0F();
    quad(0, 1);
    BARF();
    // ph3
    read_af(par, 1);
    stageB(par, 0, tp2);
    BARF(); LGKM0F();
    quad(1, 0);
    BARF();
    // ph4
    stageB(par, 1, tp2);
    VMC6F();
    BARF();
    quad(1, 1);
    BARF();
  }

  VMC0F();  // drain: stray loads write LDS, must not outlive the block
}

// ============================================================================
// Projections on the 8-phase core: y = x @ W^T. grid 192 = 3 x (16by x 4bx),
// XCD-swizzled. z=2 stores v transposed [DIM,NTOK].
// ============================================================================
__global__ __launch_bounds__(512, 2) void proj256(
    const u16* __restrict__ qxb, const u16* __restrict__ kxb, const u16* __restrict__ vxb,
    const u16* __restrict__ Wqb, const u16* __restrict__ Wkb, const u16* __restrict__ Wvb,
    u16* __restrict__ qb, u16* __restrict__ kb, u16* __restrict__ vT)
{
  __shared__ alignas(16) u16 lds[65536];  // 128 KB
  const int w = xcd_swz(blockIdx.x, 192);
  const int z = w >> 6, rem = w & 63;
  const int by = rem >> 2, bx = rem & 3;
  const u16* A = (z == 0) ? qxb : (z == 1) ? kxb : vxb;
  const u16* B = (z == 0) ? Wqb : (z == 1) ? Wkb : Wvb;
  const int row0 = by * 256, col0 = bx * 256;

  f32x4 acc[8][4] = {};
  mm256(A, B, DIM, DIM, row0, col0, DIM / 64, lds, acc);

  const int wv = threadIdx.x >> 6, lane = threadIdx.x & 63;
  const int wm = wv >> 2, wn = wv & 3;
  const int l15 = lane & 15, l4 = lane >> 4;
  const int om = row0 + wm * 128;
  const int on = col0 + wn * 64;
  if (z < 2) {
    u16* C = (z == 0) ? qb : kb;
#pragma unroll
    for (int m = 0; m < 8; ++m)
#pragma unroll
      for (int n = 0; n < 4; ++n)
#pragma unroll
        for (int r = 0; r < 4; ++r)
          C[(size_t)(om + m * 16 + l4 * 4 + r) * DIM + (on + n * 16 + l15)] = f2bf(acc[m][n][r]);
  } else {
#pragma unroll
    for (int m = 0; m < 8; ++m)
#pragma unroll
      for (int n = 0; n < 4; ++n) {
        ushort4 o;
        o.x = f2bf(acc[m][n][0]); o.y = f2bf(acc[m][n][1]);
        o.z = f2bf(acc[m][n][2]); o.w = f2bf(acc[m][n][3]);
        *reinterpret_cast<ushort4*>(&vT[(size_t)(on + n * 16 + l15) * NTOK + (om + m * 16 + l4 * 4)]) = o;
      }
  }
}

// ============================================================================
// Scores on the 8-phase core: S = (q @ k^T)*scale, bf16 out. 136 triangle
// tiles of 256x256 (bx <= by), XCD-swizzled.
// ============================================================================
__global__ __launch_bounds__(512, 2) void scores256(
    const u16* __restrict__ A, const u16* __restrict__ B, u16* __restrict__ C, float scale)
{
  __shared__ alignas(16) u16 lds[65536];  // 128 KB
  const int t = xcd_swz(blockIdx.x, 136);
  int by = (int)((sqrtf(8.0f * t + 1.0f) - 1.0f) * 0.5f);
  while ((by + 1) * (by + 2) / 2 <= t) ++by;
  while (by * (by + 1) / 2 > t) --by;
  const int bx = t - by * (by + 1) / 2;
  const int row0 = by * 256, col0 = bx * 256;

  f32x4 acc[8][4] = {};
  mm256(A, B, DIM, DIM, row0, col0, DIM / 64, lds, acc);

  const int wv = threadIdx.x >> 6, lane = threadIdx.x & 63;
  const int wm = wv >> 2, wn = wv & 3;
  const int l15 = lane & 15, l4 = lane >> 4;
  const int om = row0 + wm * 128;
  const int on = col0 + wn * 64;
#pragma unroll
  for (int m = 0; m < 8; ++m)
#pragma unroll
    for (int n = 0; n < 4; ++n)
#pragma unroll
      for (int r = 0; r < 4; ++r)
        C[(size_t)(om + m * 16 + l4 * 4 + r) * NTOK + (on + n * 16 + l15)] = f2bf(acc[m][n][r] * scale);
}

// ============================================================================
// PV core (R8-proven): BK=64, 1-deep counted-vmcnt double buffer, 4 waves.
// ============================================================================
__device__ __forceinline__ void mm64(
    const u16* __restrict__ A, const u16* __restrict__ B,
    int lda, int ldb, int klo, int khi, int row0, int col0,
    u16* sA, u16* sB, f32x4 (&acc)[2][4])
{
  constexpr int ASZ = 64 * 64, BSZ = 128 * 64;
  const int tid = threadIdx.x;
  const int wave = tid >> 6, lane = tid & 63;
  const int wr = wave >> 1, wc = wave & 1;
  const int l15 = lane & 15, l4 = lane >> 4;
  const int h = l15 & 7;

  const int srow = lane >> 3;
  const int scol = ((lane & 7) ^ (lane >> 3)) << 3;
  const u16* gA = A + (size_t)(row0 + wave * 16 + srow) * lda + scol;
  const u16* gB = B + (size_t)(col0 + wave * 32 + srow) * ldb + scol;
  const int lbA = wave * 16 * 64;
  const int lbB = wave * 32 * 64;

  auto stage = [&](int k0, u16* bA, u16* bB) {
#pragma unroll
    for (int i = 0; i < 2; ++i)
      gld16(gA + (size_t)(i * 8) * lda + k0, bA + lbA + i * 512);
#pragma unroll
    for (int i = 0; i < 4; ++i)
      gld16(gB + (size_t)(i * 8) * ldb + k0, bB + lbB + i * 512);
  };

  stage(klo, sA, sB);
  int cur = 0;
  for (int k0 = klo; k0 < khi; k0 += 64) {
    const bool more = (k0 + 64 < khi);
    if (more) {
      stage(k0 + 64, sA + (cur ^ 1) * ASZ, sB + (cur ^ 1) * BSZ);
      SFENCE(); wait_vmcnt<6>(); SFENCE();
    } else {
      SFENCE(); wait_vmcnt<0>(); SFENCE();
    }
    __builtin_amdgcn_s_barrier();
    SFENCE();

    const char* bA = (const char*)(sA + cur * ASZ);
    const char* bB = (const char*)(sB + cur * BSZ);
#pragma unroll
    for (int ks = 0; ks < 2; ++ks) {
      bf16x8 af[2], bfv[4];
#pragma unroll
      for (int mf = 0; mf < 2; ++mf)
        af[mf] = *reinterpret_cast<const bf16x8*>(
            bA + ((wr * 32 + mf * 16 + l15) << 7) + ((((ks << 2) + l4) ^ h) << 4));
#pragma unroll
      for (int nf = 0; nf < 4; ++nf)
        bfv[nf] = *reinterpret_cast<const bf16x8*>(
            bB + ((wc * 64 + nf * 16 + l15) << 7) + ((((ks << 2) + l4) ^ h) << 4));
#pragma unroll
      for (int mf = 0; mf < 2; ++mf)
#pragma unroll
        for (int nf = 0; nf < 4; ++nf)
          acc[mf][nf] = __builtin_amdgcn_mfma_f32_16x16x32_bf16(af[mf], bfv[nf], acc[mf][nf], 0, 0, 0);
    }

    SFENCE();
    __builtin_amdgcn_s_barrier();
    SFENCE();
    cur ^= 1;
  }
}

// ============================================================================
// PV: out = P @ vT^T. 64x128 tiles, 1-D grid 768 = 96 chunks x 8 bx.
// by<32: single chunk. by>=32: 2-way split-K, both halves atomicAdd into
// pre-zeroed out (zeroed by cvt6 z=6; 2 addends -> deterministic).
// ============================================================================
__global__ __launch_bounds__(256) void gemm_pv(
    const u16* __restrict__ P, const u16* __restrict__ vT, float* __restrict__ C)
{
  __shared__ alignas(16) u16 sA[2 * 64 * 64];
  __shared__ alignas(16) u16 sB[2 * 128 * 64];
  const int w = xcd_swz(blockIdx.x, 768);
  const int bx = w & 7;
  const int cid = w >> 3;  // 0..95
  int by, half;
  if (cid < 32) { by = cid; half = -1; }
  else { const int j = cid - 32; by = 32 + (j >> 1); half = j & 1; }
  const int row0 = by * 64, col0 = bx * 128;
  const int Klim = row0 + 64;
  int klo = 0, khi = Klim;
  if (half >= 0) {
    const int h1 = (((Klim >> 6) + 1) >> 1) << 6;
    if (half == 0) khi = h1; else klo = h1;
  }

  f32x4 acc[2][4] = {};
  mm64(P, vT, NTOK, NTOK, klo, khi, row0, col0, sA, sB, acc);

  const int lane = threadIdx.x & 63;
  const int wave = threadIdx.x >> 6;
  const int l15 = lane & 15, l4 = lane >> 4;
  const int om = row0 + (wave >> 1) * 32;
  const int on = col0 + (wave & 1) * 64;
#pragma unroll
  for (int mf = 0; mf < 2; ++mf)
#pragma unroll
    for (int nf = 0; nf < 4; ++nf)
#pragma unroll
      for (int r = 0; r < 4; ++r) {
        const size_t idx = (size_t)(om + mf * 16 + l4 * 4 + r) * DIM + (on + nf * 16 + l15);
        if (half >= 0) atomicAdd(&C[idx], acc[mf][nf][r]);
        else C[idx] = acc[mf][nf][r];
      }
}

// ---------- causal row softmax: S bf16 -> P bf16, cols < (row&~127)+128 ----------
__global__ __launch_bounds__(256) void softmax_causal(const u16* __restrict__ S,
                                                      u16* __restrict__ P) {
  __shared__ float buf[NTOK];
  __shared__ float red[8];
  const int row = blockIdx.x;
  const int tid = threadIdx.x;
  const int limit = row + 1;
  const int limit128 = (row & ~127) + 128;
  const u16* srow = S + (size_t)row * NTOK;

  float lmax = -1e30f;
  for (int j = tid * 8; j < limit128; j += 2048) {
    float v[8];
    if (j + 8 <= limit) {
      u16x8 sv = *reinterpret_cast<const u16x8*>(srow + j);
#pragma unroll
      for (int e = 0; e < 8; ++e) v[e] = bf2f(sv[e]);
    } else {
#pragma unroll
      for (int e = 0; e < 8; ++e) v[e] = (j + e < limit) ? bf2f(srow[j + e]) : -1e30f;
    }
    float4 lo = {v[0], v[1], v[2], v[3]}, hi = {v[4], v[5], v[6], v[7]};
    *reinterpret_cast<float4*>(buf + j) = lo;
    *reinterpret_cast<float4*>(buf + j + 4) = hi;
#pragma unroll
    for (int e = 0; e < 8; ++e) lmax = fmaxf(lmax, v[e]);
  }
  lmax = wave_max(lmax);
  if ((tid & 63) == 0) red[tid >> 6] = lmax;
  __syncthreads();
  const float m = fmaxf(fmaxf(red[0], red[1]), fmaxf(red[2], red[3]));

  float lsum = 0.f;
  for (int j = tid * 8; j < limit128; j += 2048) {
    float4 lo = *reinterpret_cast<float4*>(buf + j);
    float4 hi = *reinterpret_cast<float4*>(buf + j + 4);
    float e0 = __expf(lo.x - m), e1 = __expf(lo.y - m), e2 = __expf(lo.z - m), e3 = __expf(lo.w - m);
    float e4 = __expf(hi.x - m), e5 = __expf(hi.y - m), e6 = __expf(hi.z - m), e7 = __expf(hi.w - m);
    float4 eo = {e0, e1, e2, e3}, eh = {e4, e5, e6, e7};
    *reinterpret_cast<float4*>(buf + j) = eo;
    *reinterpret_cast<float4*>(buf + j + 4) = eh;
    lsum += ((e0 + e1) + (e2 + e3)) + ((e4 + e5) + (e6 + e7));
  }
  lsum = wave_sum(lsum);
  if ((tid & 63) == 0) red[4 + (tid >> 6)] = lsum;
  __syncthreads();
  const float inv = 1.0f / (red[4] + red[5] + red[6] + red[7]);

  u16* prow = P + (size_t)row * NTOK;
  for (int j = tid * 8; j < limit128; j += 2048) {
    float4 lo = *reinterpret_cast<float4*>(buf + j);
    float4 hi = *reinterpret_cast<float4*>(buf + j + 4);
    u16x8 o;
    o[0] = f2bf(lo.x * inv); o[1] = f2bf(lo.y * inv);
    o[2] = f2bf(lo.z * inv); o[3] = f2bf(lo.w * inv);
    o[4] = f2bf(hi.x * inv); o[5] = f2bf(hi.y * inv);
    o[6] = f2bf(hi.z * inv); o[7] = f2bf(hi.w * inv);
    *reinterpret_cast<u16x8*>(prow + j) = o;
  }
}

// ---------- launcher ----------
extern "C" void kernel_launch(void* const* d_in, const int* in_sizes, int n_in,
                              void* d_out, int out_size, void* d_ws, size_t ws_size,
                              hipStream_t stream) {
  const float* qx = (const float*)d_in[0];
  const float* kx = (const float*)d_in[1];
  const float* vx = (const float*)d_in[2];
  const float* Wq = (const float*)d_in[3];
  const float* Wk = (const float*)d_in[4];
  const float* Wv = (const float*)d_in[5];
  float* out = (float*)d_out;
  char* ws = (char*)d_ws;
  const size_t MB = 1024ull * 1024ull;

  if (ws_size < 120 * MB) {
    hipMemsetAsync(d_out, 0xFF, (size_t)out_size * sizeof(float), stream);
    return;
  }

  // ws layout: [0,30) cvt bf16 (dead after proj) | [0,32) S bf16 (after proj)
  //            [64,72) qb | [72,80) kb | [80,88) vT | [88,120) P
  u16* qxb = (u16*)(ws);
  u16* kxb = (u16*)(ws + 8 * MB);
  u16* vxb = (u16*)(ws + 16 * MB);
  u16* Wqb = (u16*)(ws + 24 * MB);
  u16* Wkb = (u16*)(ws + 26 * MB);
  u16* Wvb = (u16*)(ws + 28 * MB);
  u16* S   = (u16*)(ws);
  u16* qb  = (u16*)(ws + 64 * MB);
  u16* kb  = (u16*)(ws + 72 * MB);
  u16* vT  = (u16*)(ws + 80 * MB);
  u16* P   = (u16*)(ws + 88 * MB);

  // cvt + fused zero of out rows >= 2048 (z=6)
  cvt6<<<dim3(NTOK * DIM / (256 * 8), 1, 7), 256, 0, stream>>>(
      qx, kx, vx, Wq, Wk, Wv, qxb, kxb, vxb, Wqb, Wkb, Wvb,
      out + (size_t)2048 * DIM);

  // projections: 192 blocks of 256x256, strip-region 8-phase schedule
  proj256<<<192, 512, 0, stream>>>(qxb, kxb, vxb, Wqb, Wkb, Wvb, qb, kb, vT);

  // scores: 136 triangle tiles of 256x256, same core
  scores256<<<136, 512, 0, stream>>>(qb, kb, S, 0.03125f);

  softmax_causal<<<NTOK, 256, 0, stream>>>(S, P);

  gemm_pv<<<768, 256, 0, stream>>>(P, vT, out);
}